// Round 2
// baseline (292.699 us; speedup 1.0000x reference)
//
#include <hip/hip_runtime.h>

// SpMM: out[i,d] = sum_{e: rows[e]==i} vals[e] * x[cols[e], d]
// N=100000 nodes, E=1600000 edges, DIM=32, fp32.
//
// Round 2: atomics were the bottleneck (WRITE_SIZE 200MB = 51.2M fp32 atomic
// write-throughs). Build CSR per call in d_ws (hist -> scan -> scatter), then
// atomic-free gather: 8 lanes/row, float4 per lane, one coalesced store/row.

#define N_NODES 100000
#define N_EDGES 1600000
#define DIM 32

#define SCAN_BLOCK 1024
#define NB_SCAN ((N_NODES + SCAN_BLOCK - 1) / SCAN_BLOCK)   // 98

// ---- workspace layout (in ints) ----
// row_ptr:   [0, 102400)           (needs N+1 = 100001)
// cursor:    [102400, 204800)      (needs N)
// bsums:     [204800, 205824)      (needs NB_SCAN; padded, keeps 8B align after)
// sorted_cv: [205824, 205824+2*E)  (int2 per edge, 8B aligned: 205824*4 % 8 == 0)
#define WS_ROWPTR 0
#define WS_CURSOR 102400
#define WS_BSUMS  204800
#define WS_SORTED 205824
#define WS_TOTAL_INTS (WS_SORTED + 2 * N_EDGES)

__global__ __launch_bounds__(256) void hist_kernel(
    const int* __restrict__ rows, int* __restrict__ counts)
{
    int e = blockIdx.x * 256 + threadIdx.x;
    if (e < N_EDGES) atomicAdd(&counts[rows[e]], 1);
}

__global__ __launch_bounds__(SCAN_BLOCK) void scanA_kernel(
    int* __restrict__ data, int* __restrict__ bsums)
{
    __shared__ int lds[SCAN_BLOCK];
    int i = blockIdx.x * SCAN_BLOCK + threadIdx.x;
    int v = (i < N_NODES) ? data[i] : 0;
    lds[threadIdx.x] = v;
    __syncthreads();
    for (int off = 1; off < SCAN_BLOCK; off <<= 1) {
        int t = (threadIdx.x >= off) ? lds[threadIdx.x - off] : 0;
        __syncthreads();
        lds[threadIdx.x] += t;
        __syncthreads();
    }
    int incl = lds[threadIdx.x];
    if (i < N_NODES) data[i] = incl - v;            // exclusive within block
    if (threadIdx.x == SCAN_BLOCK - 1) bsums[blockIdx.x] = incl;
}

__global__ __launch_bounds__(128) void scanB_kernel(int* __restrict__ bsums)
{
    __shared__ int lds[128];
    int v = (threadIdx.x < NB_SCAN) ? bsums[threadIdx.x] : 0;
    lds[threadIdx.x] = v;
    __syncthreads();
    for (int off = 1; off < 128; off <<= 1) {
        int t = (threadIdx.x >= off) ? lds[threadIdx.x - off] : 0;
        __syncthreads();
        lds[threadIdx.x] += t;
        __syncthreads();
    }
    int incl = lds[threadIdx.x];
    if (threadIdx.x < NB_SCAN) bsums[threadIdx.x] = incl - v;  // exclusive
}

__global__ __launch_bounds__(SCAN_BLOCK) void scanC_kernel(
    int* __restrict__ data, const int* __restrict__ bsums, int* __restrict__ cursor)
{
    int i = blockIdx.x * SCAN_BLOCK + threadIdx.x;
    if (i < N_NODES) {
        int val = data[i] + bsums[blockIdx.x];
        data[i] = val;
        cursor[i] = val;
    }
    if (i == 0) data[N_NODES] = N_EDGES;            // row_ptr[N]
}

__global__ __launch_bounds__(256) void scatter_kernel(
    const int* __restrict__ rows, const int* __restrict__ cols,
    const float* __restrict__ vals, int* __restrict__ cursor,
    int2* __restrict__ scv)
{
    int e = blockIdx.x * 256 + threadIdx.x;
    if (e < N_EDGES) {
        int r = rows[e];
        int p = atomicAdd(&cursor[r], 1);
        scv[p] = make_int2(cols[e], __float_as_int(vals[e]));
    }
}

// 8 lanes per row; each lane owns a float4 (4 dims). 256 thr = 32 rows/block.
__global__ __launch_bounds__(256) void gather_kernel(
    const int* __restrict__ row_ptr, const int2* __restrict__ scv,
    const float4* __restrict__ x4, float4* __restrict__ out4)
{
    int tid = blockIdx.x * 256 + threadIdx.x;
    int r = tid >> 3;
    int l = tid & 7;
    if (r >= N_NODES) return;
    int beg = row_ptr[r];
    int end = row_ptr[r + 1];
    float4 acc = make_float4(0.f, 0.f, 0.f, 0.f);
    for (int e = beg; e < end; ++e) {
        int2 cv = scv[e];
        float v = __int_as_float(cv.y);
        float4 xv = x4[cv.x * 8 + l];
        acc.x += v * xv.x;
        acc.y += v * xv.y;
        acc.z += v * xv.z;
        acc.w += v * xv.w;
    }
    out4[r * 8 + l] = acc;
}

// ---- fallback (round-1 path) if ws too small ----
__global__ __launch_bounds__(256) void spmm_atomic_kernel(
    const int* __restrict__ rows, const int* __restrict__ cols,
    const float* __restrict__ vals, const float* __restrict__ x,
    float* __restrict__ out)
{
    long long idx = (long long)blockIdx.x * blockDim.x + threadIdx.x;
    if (idx >= (long long)N_EDGES * DIM) return;
    int e = (int)(idx >> 5);
    int d = (int)(idx & 31);
    atomicAdd(&out[(long long)rows[e] * DIM + d], vals[e] * x[(long long)cols[e] * DIM + d]);
}

extern "C" void kernel_launch(void* const* d_in, const int* in_sizes, int n_in,
                              void* d_out, int out_size, void* d_ws, size_t ws_size,
                              hipStream_t stream) {
    const int*   A_rows = (const int*)d_in[0];
    const int*   A_cols = (const int*)d_in[1];
    const float* A_vals = (const float*)d_in[2];
    const float* x      = (const float*)d_in[3];
    float*       out    = (float*)d_out;

    if (ws_size < (size_t)WS_TOTAL_INTS * sizeof(int)) {
        // fallback: atomic scatter (round-1 baseline)
        hipMemsetAsync(out, 0, (size_t)out_size * sizeof(float), stream);
        long long total = (long long)N_EDGES * DIM;
        spmm_atomic_kernel<<<(unsigned)((total + 255) / 256), 256, 0, stream>>>(
            A_rows, A_cols, A_vals, x, out);
        return;
    }

    int*  ws      = (int*)d_ws;
    int*  row_ptr = ws + WS_ROWPTR;
    int*  cursor  = ws + WS_CURSOR;
    int*  bsums   = ws + WS_BSUMS;
    int2* scv     = (int2*)(ws + WS_SORTED);

    // 1) zero the histogram region (ws is poisoned 0xAA every call)
    hipMemsetAsync(row_ptr, 0, (size_t)N_NODES * sizeof(int), stream);

    // 2) histogram of destination rows
    hist_kernel<<<(N_EDGES + 255) / 256, 256, 0, stream>>>(A_rows, row_ptr);

    // 3) exclusive prefix sum (two-level)
    scanA_kernel<<<NB_SCAN, SCAN_BLOCK, 0, stream>>>(row_ptr, bsums);
    scanB_kernel<<<1, 128, 0, stream>>>(bsums);
    scanC_kernel<<<NB_SCAN, SCAN_BLOCK, 0, stream>>>(row_ptr, bsums, cursor);

    // 4) bin (col,val) pairs by destination row
    scatter_kernel<<<(N_EDGES + 255) / 256, 256, 0, stream>>>(
        A_rows, A_cols, A_vals, cursor, scv);

    // 5) atomic-free gather; writes every output element (no memset needed)
    gather_kernel<<<(N_NODES * 8) / 256, 256, 0, stream>>>(
        row_ptr, scv, (const float4*)x, (float4*)out);
}